// Round 12
// baseline (142.722 us; speedup 1.0000x reference)
//
#include <hip/hip_runtime.h>
#include <hip/hip_bf16.h>
#include <stdint.h>

#define NB 8192
#define DK 256
// gamma * log2(e): epilogue uses native exp2
#define GSCALE 14.426950408889634f

typedef short short8 __attribute__((ext_vector_type(8)));
typedef float f32x4 __attribute__((ext_vector_type(4)));

__device__ __forceinline__ unsigned short f32_to_bf16(float f) {
  uint32_t u = __builtin_bit_cast(uint32_t, f);
  u += 0x7FFFu + ((u >> 16) & 1u);   // RNE
  return (unsigned short)(u >> 16);
}

// Normalize (gamma*log2e folded into e side) AND write in PACKED MFMA-fragment
// layout: fragment (row-panel p = r>>4, ks = k>>5) is a contiguous 1-KB chunk;
// lane l owns bytes l*16..+16 = row p*16+(r&15), k = ks*32 + (l>>4)*8 ..+8.
// packed_byte(r,k) = (r>>4)*8192 + (k>>5)*1024 + ((k>>3)&3)*256 + (r&15)*16 + (k&7)*2.
// Blocks 0..15 also zero d_out (replaces hipMemsetAsync).
__global__ __launch_bounds__(256) void normpack_kernel(const float* __restrict__ e,
                                                       const float* __restrict__ v,
                                                       unsigned short* __restrict__ apk,
                                                       unsigned short* __restrict__ vpk,
                                                       float* __restrict__ out) {
  if (blockIdx.x < 16) {
    float4 z = {0.f, 0.f, 0.f, 0.f};
    reinterpret_cast<float4*>(out)[blockIdx.x * 256 + threadIdx.x] = z;
  }
  int wave = threadIdx.x >> 6;
  int lane = threadIdx.x & 63;
  int row = blockIdx.x * 4 + wave;          // 0..16383
  const float* src;
  unsigned short* dstbase;
  float mul;
  if (row < NB) {
    src = e + (size_t)row * DK; dstbase = apk; mul = GSCALE;
  } else {
    row -= NB;
    src = v + (size_t)row * DK; dstbase = vpk; mul = 1.0f;
  }
  float4 x = reinterpret_cast<const float4*>(src)[lane];   // k = 4*lane .. +3
  float ss = x.x * x.x + x.y * x.y + x.z * x.z + x.w * x.w;
  #pragma unroll
  for (int off = 32; off >= 1; off >>= 1) ss += __shfl_xor(ss, off);
  float s = mul / fmaxf(sqrtf(ss), 1e-8f);
  ushort4 o;
  o.x = f32_to_bf16(x.x * s);
  o.y = f32_to_bf16(x.y * s);
  o.z = f32_to_bf16(x.z * s);
  o.w = f32_to_bf16(x.w * s);
  size_t off = (size_t)(row >> 4) * 8192 + (size_t)(lane >> 3) * 1024 +
               ((lane >> 1) & 3) * 256 + (row & 15) * 16 + (lane & 1) * 8;
  *reinterpret_cast<ushort4*>((char*)dstbase + off) = o;
}

// Persistent (R11 structure) with R8's non-spilling loop shape: DYNAMIC
// j-loop (8 iters), statically-unrolled 8-step inner, 4-slot register ring
// with all indices compile-time. 1024 blocks (4/CU, 16 waves/CU), block =
// 64 rows x 1024 cols; wave = 64 rows x 32 cols per j-tile. A panel staged
// to LDS once (linear packed copy, conflict-free reads by construction);
// B frags stream from the per-XCD L2-resident 512-KB slice; cross-j
// prefetch keeps the ring full through the per-j epilogue. Col sums: plain
// LDS writes (lgkm domain). Row sums: registers. Global atomics: tail burst.
__global__ __launch_bounds__(256, 4) void score_kernel(const unsigned short* __restrict__ apk,
                                                       const unsigned short* __restrict__ vpk,
                                                       float* __restrict__ out) {
  __shared__ unsigned short As[16384];      // 32 KB packed A panel
  __shared__ float colsum[1024];            // 4 KB (each slot written once)
  __shared__ float rowsum[4][64];           // 1 KB

  const int tid = threadIdx.x;
  const int w = tid >> 6;          // 0..3 (col quarter within j-tile)
  const int lane = tid & 63;
  const int lo16 = lane & 15;
  const int q4 = lane >> 4;        // 0..3

  int id = blockIdx.x;             // 1024 blocks
  int colgroup = id & 7;           // 0..7   (1024-col group; ~1 per XCD)
  int rowblk = id >> 3;            // 0..127 (64-row panel)

  // ---- Stage A panel: 32 KB, pure linear copy of packed fragments ----
  const char* aP = (const char*)apk + (size_t)rowblk * 32768;
  #pragma unroll
  for (int u = 0; u < 8; ++u) {
    int chunk = w * 8 + u;                     // 0..31 (1-KB fragments)
    const char* src = aP + chunk * 1024 + lane * 16;
    unsigned short* dst = &As[chunk * 512];
    __builtin_amdgcn_global_load_lds((const __attribute__((address_space(1))) uint32_t*)src,
                                     (__attribute__((address_space(3))) uint32_t*)dst, 16, 0, 0);
  }

  // ---- B ring prologue: this wave's col-panel pair, j=0, ks=0..2 ----
  // wave cols at tile j: colgroup*1024 + j*128 + w*32 (+ n*16)
  // frag byte offset from p0: j*65536 + n*8192 + ks*1024
  const char* p0 = (const char*)vpk + (size_t)(colgroup * 64 + w * 2) * 8192 + lane * 16;

  short8 S[4][2];
  #pragma unroll
  for (int s = 0; s < 3; ++s) {
    S[s][0] = *(const short8*)(p0 + s * 1024);
    S[s][1] = *(const short8*)(p0 + 8192 + s * 1024);
  }

  __syncthreads();   // drains glds (vmcnt) + barrier; one-time cost

  f32x4 acc[4][2];
  #pragma unroll
  for (int m = 0; m < 4; ++m)
    #pragma unroll
    for (int n = 0; n < 2; ++n)
      #pragma unroll
      for (int q = 0; q < 4; ++q)
        acc[m][n][q] = 0.0f;

  float rowAcc[4][4];
  #pragma unroll
  for (int m = 0; m < 4; ++m)
    #pragma unroll
    for (int g = 0; g < 4; ++g)
      rowAcc[m][g] = 0.0f;

  const char* pj = p0;
  for (int j = 0; j < 8; ++j) {            // DYNAMIC: small body, no spill
    const char* pnext = (j < 7) ? pj + 65536 : pj;   // wrap-safe
    #pragma unroll
    for (int ks = 0; ks < 8; ++ks) {       // static: slot indices compile-time
      // prefetch into slot (ks+3)&3: same-j frags for ks<5, next-j ks0..2 after
      {
        const char* psrc = (ks < 5) ? (pj + (ks + 3) * 1024) : (pnext + (ks - 5) * 1024);
        S[(ks + 3) & 3][0] = *(const short8*)(psrc);
        S[(ks + 3) & 3][1] = *(const short8*)(psrc + 8192);
      }
      short8 af[4];
      #pragma unroll
      for (int m = 0; m < 4; ++m)
        af[m] = *(const short8*)((const char*)As + (m * 8 + ks) * 1024 + lane * 16);
      #pragma unroll
      for (int m = 0; m < 4; ++m) {
        acc[m][0] = __builtin_amdgcn_mfma_f32_16x16x32_bf16(af[m], S[ks & 3][0], acc[m][0], 0, 0, 0);
        acc[m][1] = __builtin_amdgcn_mfma_f32_16x16x32_bf16(af[m], S[ks & 3][1], acc[m][1], 0, 0, 0);
      }
    }
    pj = pnext;

    // ---- per-j epilogue (next tile's ks0..2 already in flight):
    // E = exp2(acc); rows -> regs (across all j), cols -> plain LDS write.
    // C/D layout: col = lane&15 (B side), row = (lane>>4)*4 + reg (A side).
    float colpart[2] = {0.f, 0.f};
    #pragma unroll
    for (int m = 0; m < 4; ++m)
      #pragma unroll
      for (int n = 0; n < 2; ++n)
        #pragma unroll
        for (int g2 = 0; g2 < 4; ++g2) {
          float ev = __builtin_amdgcn_exp2f(acc[m][n][g2]);
          rowAcc[m][g2] += ev;
          colpart[n] += ev;
          acc[m][n][g2] = 0.0f;
        }
    #pragma unroll
    for (int n = 0; n < 2; ++n) {
      float cs = colpart[n];
      cs += __shfl_xor(cs, 16);
      cs += __shfl_xor(cs, 32);
      if (q4 == n) {
        colsum[j * 128 + w * 32 + n * 16 + lo16] = cs;   // written exactly once
      }
    }
  }

  // ---- rows: reduce over 16 cols; lane lo16==m*4+g holds row m*16+q4*4+g ----
  #pragma unroll
  for (int m = 0; m < 4; ++m)
    #pragma unroll
    for (int g = 0; g < 4; ++g) {
      float rs = rowAcc[m][g];
      rs += __shfl_xor(rs, 1);
      rs += __shfl_xor(rs, 2);
      rs += __shfl_xor(rs, 4);
      rs += __shfl_xor(rs, 8);
      if (lo16 == m * 4 + g) {
        rowsum[w][m * 16 + q4 * 4 + g] = rs;
      }
    }

  __syncthreads();

  // ---- tail: all global atomics in one dependent-free burst ----
  #pragma unroll
  for (int k = 0; k < 4; ++k) {
    int c = tid + k * 256;
    atomicAdd(&out[NB + colgroup * 1024 + c], colsum[c]);
  }
  if (tid < 64) {
    float s = rowsum[0][tid] + rowsum[1][tid] + rowsum[2][tid] + rowsum[3][tid];
    atomicAdd(&out[rowblk * 64 + tid], s);
  }
}

extern "C" void kernel_launch(void* const* d_in, const int* in_sizes, int n_in,
                              void* d_out, int out_size, void* d_ws, size_t ws_size,
                              hipStream_t stream) {
  const float* e = (const float*)d_in[0];
  const float* v = (const float*)d_in[1];
  float* out = (float*)d_out;
  unsigned short* apk = (unsigned short*)d_ws;                 // 4 MiB packed e
  unsigned short* vpk = apk + (size_t)NB * DK;                 // 4 MiB packed v
  hipLaunchKernelGGL(normpack_kernel, dim3((2 * NB) / 4), dim3(256), 0, stream, e, v, apk, vpk, out);
  hipLaunchKernelGGL(score_kernel, dim3(1024), dim3(256), 0, stream, apk, vpk, out);
}

// Round 13
// 67.061 us; speedup vs baseline: 2.1282x; 2.1282x over previous
//
#include <hip/hip_runtime.h>
#include <hip/hip_bf16.h>
#include <stdint.h>

#define NB 8192
#define DK 256
// gamma * log2(e): epilogue uses native exp2
#define GSCALE 14.426950408889634f

typedef short short8 __attribute__((ext_vector_type(8)));
typedef float f32x4 __attribute__((ext_vector_type(4)));

__device__ __forceinline__ unsigned short f32_to_bf16(float f) {
  uint32_t u = __builtin_bit_cast(uint32_t, f);
  u += 0x7FFFu + ((u >> 16) & 1u);   // RNE
  return (unsigned short)(u >> 16);
}

// Normalize (gamma*log2e folded into e side) AND write in PACKED MFMA-fragment
// layout: fragment (row-panel p = r>>4, ks = k>>5) is a contiguous 1-KB chunk;
// lane l owns bytes l*16..+16 = row p*16+(r&15), k = ks*32 + (l>>4)*8 ..+8.
// packed_byte(r,k) = (r>>4)*8192 + (k>>5)*1024 + ((k>>3)&3)*256 + (r&15)*16 + (k&7)*2.
// Blocks 0..15 also zero d_out (replaces hipMemsetAsync).
__global__ __launch_bounds__(256) void normpack_kernel(const float* __restrict__ e,
                                                       const float* __restrict__ v,
                                                       unsigned short* __restrict__ apk,
                                                       unsigned short* __restrict__ vpk,
                                                       float* __restrict__ out) {
  if (blockIdx.x < 16) {
    float4 z = {0.f, 0.f, 0.f, 0.f};
    reinterpret_cast<float4*>(out)[blockIdx.x * 256 + threadIdx.x] = z;
  }
  int wave = threadIdx.x >> 6;
  int lane = threadIdx.x & 63;
  int row = blockIdx.x * 4 + wave;          // 0..16383
  const float* src;
  unsigned short* dstbase;
  float mul;
  if (row < NB) {
    src = e + (size_t)row * DK; dstbase = apk; mul = GSCALE;
  } else {
    row -= NB;
    src = v + (size_t)row * DK; dstbase = vpk; mul = 1.0f;
  }
  float4 x = reinterpret_cast<const float4*>(src)[lane];   // k = 4*lane .. +3
  float ss = x.x * x.x + x.y * x.y + x.z * x.z + x.w * x.w;
  #pragma unroll
  for (int off = 32; off >= 1; off >>= 1) ss += __shfl_xor(ss, off);
  float s = mul / fmaxf(sqrtf(ss), 1e-8f);
  ushort4 o;
  o.x = f32_to_bf16(x.x * s);
  o.y = f32_to_bf16(x.y * s);
  o.z = f32_to_bf16(x.z * s);
  o.w = f32_to_bf16(x.w * s);
  size_t off = (size_t)(row >> 4) * 8192 + (size_t)(lane >> 3) * 1024 +
               ((lane >> 1) & 3) * 256 + (row & 15) * 16 + (lane & 1) * 8;
  *reinterpret_cast<ushort4*>((char*)dstbase + off) = o;
}

// R10 structure (fully static body -- the only codegen shape that hasn't
// spilled) with wave tile widened 64x32 -> 64x64: 4 ds_read : 16 MFMA halves
// the LDS floor (20.5 -> 10.2 us) and halves A-panel L2 refetch (4096 blocks).
// Block = 64 rows x 256 cols, 4 waves (same rows, disjoint 64-col groups);
// A panel (32 KB packed) staged to LDS once, linear copy, conflict-free
// reads by construction. B: 4 coalesced 1-KB fragment loads/step through a
// static ping-pong pair S[2][4]; one K=256 pass; single end epilogue; no
// in-loop barriers; TLP 12 waves/CU (launch_bounds(256,3), 170-reg cap).
__global__ __launch_bounds__(256, 3) void score_kernel(const unsigned short* __restrict__ apk,
                                                       const unsigned short* __restrict__ vpk,
                                                       float* __restrict__ out) {
  __shared__ unsigned short As[16384];      // 32 KB packed A panel
  __shared__ float rowsum[4][64];           // 1 KB

  const int tid = threadIdx.x;
  const int w = tid >> 6;          // 0..3 (64-col group within block)
  const int lane = tid & 63;
  const int lo16 = lane & 15;
  const int q4 = lane >> 4;        // 0..3

  // 4096 blocks: xcd = id&7; per XCD 4 colblks (512 KB B hot-set, L2-resident),
  // consecutive t walk rowblks within a colblk.
  int id = blockIdx.x;
  int xcd = id & 7;
  int t = id >> 3;                      // 0..511
  int colblk = (xcd << 2) | (t & 3);    // 0..31  (256-col strip)
  int rowblk = t >> 2;                  // 0..127 (64-row panel)

  // ---- Stage A panel: 32 KB, pure linear copy of packed fragments ----
  const char* aP = (const char*)apk + (size_t)rowblk * 32768;
  #pragma unroll
  for (int u = 0; u < 8; ++u) {
    int chunk = w * 8 + u;                     // 0..31 (1-KB fragments)
    const char* src = aP + chunk * 1024 + lane * 16;
    unsigned short* dst = &As[chunk * 512];
    __builtin_amdgcn_global_load_lds((const __attribute__((address_space(1))) uint32_t*)src,
                                     (__attribute__((address_space(3))) uint32_t*)dst, 16, 0, 0);
  }

  // ---- B ping-pong prologue: wave's 4 col-panels (cp = colblk*16 + w*4 + n),
  //      frag byte = n*8192 + ks*1024; steps 0 and 1 in flight ----
  const char* p0 = (const char*)vpk + (size_t)(colblk * 16 + w * 4) * 8192 + lane * 16;

  short8 S[2][4];
  #pragma unroll
  for (int n = 0; n < 4; ++n) {
    S[0][n] = *(const short8*)(p0 + n * 8192);
    S[1][n] = *(const short8*)(p0 + n * 8192 + 1024);
  }

  asm volatile("s_waitcnt vmcnt(0)" ::: "memory");   // A-panel writes done
  __builtin_amdgcn_s_barrier();
  asm volatile("" ::: "memory");

  f32x4 acc[4][4];
  #pragma unroll
  for (int m = 0; m < 4; ++m)
    #pragma unroll
    for (int n = 0; n < 4; ++n)
      #pragma unroll
      for (int q = 0; q < 4; ++q)
        acc[m][n][q] = 0.0f;

  // ---- K loop: 8 static steps, no barriers. Ping-pong: step ks consumes
  //      S[ks&1]; after consumption the slot is refilled for step ks+2. ----
  #pragma unroll
  for (int ks = 0; ks < 8; ++ks) {
    short8 af[4];
    #pragma unroll
    for (int m = 0; m < 4; ++m)
      af[m] = *(const short8*)((const char*)As + (m * 8 + ks) * 1024 + lane * 16);
    #pragma unroll
    for (int n = 0; n < 4; ++n)
      #pragma unroll
      for (int m = 0; m < 4; ++m)
        acc[m][n] = __builtin_amdgcn_mfma_f32_16x16x32_bf16(af[m], S[ks & 1][n], acc[m][n], 0, 0, 0);
    if (ks < 6) {                              // refill consumed slot for ks+2
      #pragma unroll
      for (int n = 0; n < 4; ++n)
        S[ks & 1][n] = *(const short8*)(p0 + n * 8192 + (ks + 2) * 1024);
    }
  }

  // ---- epilogue: E = exp2(acc); rows -> LDS merge, cols -> atomics.
  // C/D layout: col = n*16 + (lane&15), row = m*16 + (lane>>4)*4 + reg.
  float colpart[4] = {0.f, 0.f, 0.f, 0.f};
  float rp[4][4];
  #pragma unroll
  for (int m = 0; m < 4; ++m)
    #pragma unroll
    for (int g = 0; g < 4; ++g)
      rp[m][g] = 0.0f;

  #pragma unroll
  for (int m = 0; m < 4; ++m)
    #pragma unroll
    for (int n = 0; n < 4; ++n)
      #pragma unroll
      for (int g = 0; g < 4; ++g) {
        float ev = __builtin_amdgcn_exp2f(acc[m][n][g]);
        rp[m][g] += ev;
        colpart[n] += ev;
      }

  // rows: reduce over the 16 cols of each group; lane lo16==m*4+g holds
  // row m*16 + q4*4 + g
  #pragma unroll
  for (int m = 0; m < 4; ++m)
    #pragma unroll
    for (int g = 0; g < 4; ++g) {
      float rs = rp[m][g];
      rs += __shfl_xor(rs, 1);
      rs += __shfl_xor(rs, 2);
      rs += __shfl_xor(rs, 4);
      rs += __shfl_xor(rs, 8);
      if (lo16 == m * 4 + g) {
        rowsum[w][m * 16 + q4 * 4 + g] = rs;
      }
    }

  // cols: colpart[n] covers q4's 16 rows; sum the 4 q4 copies, lane-group n
  // writes its 16 cols
  #pragma unroll
  for (int n = 0; n < 4; ++n) {
    float cs = colpart[n];
    cs += __shfl_xor(cs, 16);
    cs += __shfl_xor(cs, 32);
    if (q4 == n) {
      atomicAdd(&out[NB + colblk * 256 + w * 64 + n * 16 + lo16], cs);
    }
  }

  __syncthreads();
  // rows: merge the 4 waves' copies (same 64 rows), one atomic per row
  if (tid < 64) {
    float s = rowsum[0][tid] + rowsum[1][tid] + rowsum[2][tid] + rowsum[3][tid];
    atomicAdd(&out[rowblk * 64 + tid], s);
  }
}

extern "C" void kernel_launch(void* const* d_in, const int* in_sizes, int n_in,
                              void* d_out, int out_size, void* d_ws, size_t ws_size,
                              hipStream_t stream) {
  const float* e = (const float*)d_in[0];
  const float* v = (const float*)d_in[1];
  float* out = (float*)d_out;
  unsigned short* apk = (unsigned short*)d_ws;                 // 4 MiB packed e
  unsigned short* vpk = apk + (size_t)NB * DK;                 // 4 MiB packed v
  hipLaunchKernelGGL(normpack_kernel, dim3((2 * NB) / 4), dim3(256), 0, stream, e, v, apk, vpk, out);
  hipLaunchKernelGGL(score_kernel, dim3(4096), dim3(256), 0, stream, apk, vpk, out);
}